// Round 3
// baseline (108.130 us; speedup 1.0000x reference)
//
#include <hip/hip_runtime.h>
#include <hip/hip_bf16.h>
#include <math.h>

// B=256, N=256, E=512, ITER=10
#define Bb   256
#define Nn   256
#define Ee   512
#define TK   128            // K-chunk (bf16) staged in LDS
#define NCH  (Ee / TK)      // 4 chunks
#define KST  (TK / 32)      // 4 mfma k-steps per chunk (K=32 each)
#define NITER 10

typedef __attribute__((ext_vector_type(8))) short bf16x8;   // MFMA A/B frag (4 VGPR)
typedef __attribute__((ext_vector_type(4))) float f32x4;    // MFMA C/D frag

static __device__ __forceinline__ unsigned short f2bf(float f) {
    __hip_bfloat16 h = __float2bfloat16(f);        // RNE, compiler emits v_cvt_pk pairs
    return __builtin_bit_cast(unsigned short, h);
}

// LDS tile: bf16 [256 rows][128 k], row stride 256B, XOR swizzle (T2):
// byte ^= (row&7)<<4 -> per-row-strided b128 reads spread across 8 16B slots (<=2-way).
static __device__ __forceinline__ int tile_byte(int row, int kelem) {
    int byteoff = row * 256 + kelem * 2;
    return byteoff ^ ((row & 7) << 4);
}

// 512 threads = 8 waves in a 4x2 grid; wave (wr,wc) owns rows [wr*64,+64) x
// cols [wc*128,+128) of C = F F^T.  acc[4][8] f32x4 = 128 VGPR/thread; with
// 8-wave blocks a resident block is 2 waves/SIMD -> 256-VGPR budget -> no spill
// (the round-2 kernel's 16-wave blocks capped the budget at 128 and spilled).
__global__ __launch_bounds__(512, 2) void crf_mfma(
    const float* __restrict__ feats,   // [B, N, E]
    const float* __restrict__ logits,  // [B, N, 1]
    const float* __restrict__ W,       // [1, N, N]
    float* __restrict__ out)           // [B, N, 1]
{
    const int b    = blockIdx.x;
    const int t    = threadIdx.x;
    const int wave = t >> 6;           // 0..7
    const int lane = t & 63;
    const int wr   = wave >> 1;        // 0..3 (64-row block)
    const int wc   = wave & 1;         // 0..1 (128-col block)
    const int lo   = lane & 15;        // C/D col = lo; A/B row/col = lo
    const int hi   = lane >> 4;        // C/D row = hi*4+reg; A/B k-base = hi*8

    __shared__ unsigned char tileb[2][Nn * 256];  // 2 x 64 KB bf16 chunk (double buffer)
    __shared__ float invn[Nn];
    __shared__ float svec[Nn];
    __shared__ float uvec[Nn];
    __shared__ float lgv[Nn];
    __shared__ float part[4][Nn];

    f32x4 acc[4][8];
#pragma unroll
    for (int i = 0; i < 4; ++i)
#pragma unroll
        for (int j = 0; j < 8; ++j) acc[i][j] = (f32x4){0.f, 0.f, 0.f, 0.f};

    const float* Fb = feats + (size_t)b * Nn * Ee;

    // stage chunk ch (fp32 -> bf16) into tileb[buf]; 16 float4 loads/thread
    auto stage = [&](int ch, int buf) {
#pragma unroll
        for (int it = 0; it < 16; ++it) {
            const int flat = it * 512 + t;
            const int n  = flat >> 5;          // row 0..255
            const int c4 = flat & 31;          // float4 col 0..31
            const float4 v = *reinterpret_cast<const float4*>(
                Fb + (size_t)n * Ee + ch * TK + c4 * 4);
            ushort4 pk;
            pk.x = f2bf(v.x); pk.y = f2bf(v.y); pk.z = f2bf(v.z); pk.w = f2bf(v.w);
            *reinterpret_cast<ushort4*>(tileb[buf] + tile_byte(n, c4 * 4)) = pk;
        }
    };

    // ================= GEMM: C = F F^T, double-buffered chunks =================
    stage(0, 0);
    if (t < Nn) {
        const float u = logits[(size_t)b * Nn + t];
        uvec[t] = u;
        lgv[t]  = u;
    }
    __syncthreads();

    for (int ch = 0; ch < NCH; ++ch) {
        const int buf = ch & 1;
        if (ch + 1 < NCH) stage(ch + 1, buf ^ 1);   // issue next-chunk loads first
        const unsigned char* tb = tileb[buf];
#pragma unroll
        for (int ks = 0; ks < KST; ++ks) {
            const int kb = ks * 32 + hi * 8;
            bf16x8 af[4], bfv[8];
#pragma unroll
            for (int rb = 0; rb < 4; ++rb)
                af[rb] = *reinterpret_cast<const bf16x8*>(
                    tb + tile_byte(wr * 64 + rb * 16 + lo, kb));
#pragma unroll
            for (int cb = 0; cb < 8; ++cb)
                bfv[cb] = *reinterpret_cast<const bf16x8*>(
                    tb + tile_byte(wc * 128 + cb * 16 + lo, kb));
#pragma unroll
            for (int rb = 0; rb < 4; ++rb)
#pragma unroll
                for (int cb = 0; cb < 8; ++cb)
                    acc[rb][cb] = __builtin_amdgcn_mfma_f32_16x16x32_bf16(
                        af[rb], bfv[cb], acc[rb][cb], 0, 0, 0);
        }
        __syncthreads();
    }

    // ================= inverse norms from the diagonal =================
    // diag subtile of row-block (wr,rb) lives in wave (wr, wc=wr>>1) at cb=(wr&1)*4+rb
    if (wc == (wr >> 1)) {
#pragma unroll
        for (int rb = 0; rb < 4; ++rb) {
            if (hi == (lo >> 2)) {                 // lane holding subtile elem (lo,lo)
                const int cbd = (wr & 1) * 4 + rb;
                const f32x4 a = acc[rb][cbd];
                const int reg = lo & 3;
                const float d = (reg == 0) ? a[0] : (reg == 1) ? a[1]
                              : (reg == 2) ? a[2] : a[3];
                invn[wr * 64 + rb * 16 + lo] = 1.0f / sqrtf(d);
            }
        }
    }
    __syncthreads();

    // ================= P = C * invn_r * invn_c * 0.5*(W[r][c]+W[c][r]) =================
#pragma unroll
    for (int rb = 0; rb < 4; ++rb) {
        const int rbase = wr * 64 + rb * 16 + hi * 4;
        const float4 ir4 = *reinterpret_cast<const float4*>(&invn[rbase]);
        const float ir[4] = {ir4.x, ir4.y, ir4.z, ir4.w};
#pragma unroll
        for (int cb = 0; cb < 8; ++cb) {
            const int col = wc * 128 + cb * 16 + lo;
            const float ic = invn[col];
#pragma unroll
            for (int r = 0; r < 4; ++r) {
                const int row = rbase + r;
                const float wsym = 0.5f * (W[row * Nn + col] + W[col * Nn + row]);
                acc[rb][cb][r] = acc[rb][cb][r] * ir[r] * ic * wsym;
            }
        }
    }

    // ================= 10 mean-field iterations =================
    // P symmetric -> e[col] = sum_row P[row][col]*s[row]: in-lane over 16 rows,
    // butterfly over hi-groups, LDS partial over the 4 wr row-blocks.
    for (int itr = 0; itr < NITER; ++itr) {
        if (t < Nn) {
            const float x = lgv[t];
            svec[t] = 2.f / (1.f + __expf(-x)) - 1.f;
        }
        __syncthreads();

        float ep[8] = {0.f, 0.f, 0.f, 0.f, 0.f, 0.f, 0.f, 0.f};
#pragma unroll
        for (int rb = 0; rb < 4; ++rb) {
            const float4 s4 = *reinterpret_cast<const float4*>(
                &svec[wr * 64 + rb * 16 + hi * 4]);
#pragma unroll
            for (int cb = 0; cb < 8; ++cb)
                ep[cb] += acc[rb][cb][0] * s4.x + acc[rb][cb][1] * s4.y
                        + acc[rb][cb][2] * s4.z + acc[rb][cb][3] * s4.w;
        }
#pragma unroll
        for (int cb = 0; cb < 8; ++cb) {
            ep[cb] += __shfl_xor(ep[cb], 16);
            ep[cb] += __shfl_xor(ep[cb], 32);
        }
        if (lane < 16) {
#pragma unroll
            for (int cb = 0; cb < 8; ++cb)
                part[wr][wc * 128 + cb * 16 + lane] = ep[cb];
        }
        __syncthreads();
        if (t < Nn)
            lgv[t] = uvec[t] + part[0][t] + part[1][t] + part[2][t] + part[3][t];
        // next iteration's part writes are after its own barrier; lgv[t] is
        // read only by the thread that wrote it -> no trailing barrier needed.
    }

    if (t < Nn) out[(size_t)b * Nn + t] = lgv[t];
}

extern "C" void kernel_launch(void* const* d_in, const int* in_sizes, int n_in,
                              void* d_out, int out_size, void* d_ws, size_t ws_size,
                              hipStream_t stream) {
    const float* feats  = (const float*)d_in[0];
    const float* logits = (const float*)d_in[1];
    const float* W      = (const float*)d_in[2];
    float* out = (float*)d_out;

    crf_mfma<<<dim3(Bb), dim3(512), 0, stream>>>(feats, logits, W, out);
}